// Round 15
// baseline (468.995 us; speedup 1.0000x reference)
//
#include <hip/hip_runtime.h>
#include <math.h>

#define Bd 4
#define Cd 512
#define Hd 48
#define Wd 48
#define HWd (Hd * Wd)          // 2304
#define Nd (Bd * HWd)          // 9216
#define BN_EPS 1e-5f

#define QBLK 64
#define KBLK 128
#define NKS 4
#define KSLEN (Nd / NKS)       // 2304
#define AITERS (KSLEN / KBLK)  // 18

typedef _Float16 half8 __attribute__((ext_vector_type(8)));
typedef _Float16 h4 __attribute__((ext_vector_type(4)));
typedef float f32x16 __attribute__((ext_vector_type(16)));

__device__ inline void gload_lds16(const void* g, void* l) {
    __builtin_amdgcn_global_load_lds((const __attribute__((address_space(1))) void*)g,
                                     (__attribute__((address_space(3))) void*)l, 16, 0, 0);
}

// ---- shared packed-layout index functions, writer==reader ----
__device__ inline size_t wp_idx(int o, int c) {
    return (((size_t)(o >> 5) * 32 + (c >> 4)) * 64 + ((o & 31) + 32 * ((c >> 3) & 1))) * 8 + (c & 7);
}
__device__ inline size_t qp_idx(int q, int c) {
    return (((size_t)(q >> 5) * 64 + (c >> 3)) * 32 + (q & 31)) * 8 + (c & 7);
}
__device__ inline size_t kp_idx(int n, int o) {
    return ((((size_t)(n >> 7) * 4 + ((n >> 5) & 3)) * 32 + (o >> 4)) * 64
            + ((n & 31) + 32 * ((o >> 3) & 1))) * 8 + (o & 7);
}
__device__ inline size_t vp_idx(int n, int o) {
    return ((((size_t)(n >> 7) * 16 + (o >> 5)) * 8 + ((n >> 4) & 7)) * 64
            + ((o & 31) + 32 * ((n >> 3) & 1))) * 8 + (n & 7);
}

// ---------------- weight pack: f32 [512][512] -> fp16 fragment order ----------------
__global__ __launch_bounds__(256) void wpack_k(const float* __restrict__ w0,
                                               const float* __restrict__ w1,
                                               const float* __restrict__ w2,
                                               const float* __restrict__ w3,
                                               _Float16* __restrict__ p0,
                                               _Float16* __restrict__ p1,
                                               _Float16* __restrict__ p2,
                                               _Float16* __restrict__ p3) {
    const float* w; _Float16* p;
    switch (blockIdx.y) {
        case 0: w = w0; p = p0; break;
        case 1: w = w1; p = p1; break;
        case 2: w = w2; p = p2; break;
        default: w = w3; p = p3; break;
    }
    int idx = blockIdx.x * 256 + threadIdx.x;
    int o = idx >> 6;
    int cc = (idx & 63) * 8;
    float4 a = *(const float4*)(w + (size_t)o * 512 + cc);
    float4 b = *(const float4*)(w + (size_t)o * 512 + cc + 4);
    half8 v = {(_Float16)a.x, (_Float16)a.y, (_Float16)a.z, (_Float16)a.w,
               (_Float16)b.x, (_Float16)b.y, (_Float16)b.z, (_Float16)b.w};
    *(half8*)(p + wp_idx(o, cc)) = v;
}

// ---------------- MFMA linear (1x1 conv): 32-token tile, 256-o half ----------------
template<int INM, int OUTM>
__global__ __launch_bounds__(256, 2) void linproj_k(const void* __restrict__ in,
                                                    const _Float16* __restrict__ Wp,
                                                    const float* __restrict__ bias,
                                                    void* __restrict__ outp) {
    constexpr bool SWAP = (OUTM == 2);
    __shared__ _Float16 Xs[16384];

    const int tid = threadIdx.x;
    const int wave = tid >> 6;
    const int lane = tid & 63;
    const int l31 = lane & 31;
    const int hi32 = lane >> 5;
    const int n0 = blockIdx.x * 32;
    const int by = blockIdx.y;
    const int b = n0 / HWd;
    const int hw0 = n0 % HWd;

    {
        const int t = tid & 31;
        const int c0 = tid >> 5;
        #pragma unroll 8
        for (int k = 0; k < 64; ++k) {
            int c = c0 + 8 * k;
            float val;
            if (INM == 0)
                val = ((const float*)in)[(size_t)(b * Cd + c) * HWd + hw0 + t];
            else
                val = (float)((const _Float16*)in)[(size_t)c * Nd + n0 + t];
            if (!SWAP)
                Xs[(c >> 3) * 256 + t * 8 + (c & 7)] = (_Float16)val;
            else
                Xs[(c >> 4) * 512 + (t + 32 * ((c >> 3) & 1)) * 8 + (c & 7)] = (_Float16)val;
        }
    }
    __syncthreads();

    #pragma unroll
    for (int ot = 0; ot < 2; ++ot) {
        const int otb = by * 256 + ot * 128 + wave * 32;

        half8 wa[32];
        const _Float16* wpb = Wp + ((size_t)(otb >> 5) * 32) * 512;
        #pragma unroll
        for (int f = 0; f < 32; ++f)
            wa[f] = *(const half8*)(wpb + (size_t)f * 512 + lane * 8);

        f32x16 acc;
        #pragma unroll
        for (int r = 0; r < 16; ++r) acc[r] = 0.f;

        __builtin_amdgcn_s_setprio(1);
        #pragma unroll
        for (int f = 0; f < 32; ++f) {
            if (!SWAP) {
                half8 xb = *(const half8*)(Xs + (2 * f + hi32) * 256 + l31 * 8);
                acc = __builtin_amdgcn_mfma_f32_32x32x16_f16(wa[f], xb, acc, 0, 0, 0);
            } else {
                half8 xa = *(const half8*)(Xs + f * 512 + lane * 8);
                acc = __builtin_amdgcn_mfma_f32_32x32x16_f16(xa, wa[f], acc, 0, 0, 0);
            }
        }
        __builtin_amdgcn_s_setprio(0);

        if (OUTM == 0) {
            _Float16* Qp = (_Float16*)outp;
            #pragma unroll
            for (int q8 = 0; q8 < 4; ++q8) {
                int o = otb + 8 * q8 + 4 * hi32;
                float4 bv = *(const float4*)(bias + o);
                h4 v = {(_Float16)(acc[4 * q8 + 0] + bv.x), (_Float16)(acc[4 * q8 + 1] + bv.y),
                        (_Float16)(acc[4 * q8 + 2] + bv.z), (_Float16)(acc[4 * q8 + 3] + bv.w)};
                *(h4*)(Qp + qp_idx(n0 + l31, o)) = v;
            }
        } else if (OUTM == 1) {
            _Float16* Kp = (_Float16*)outp;
            #pragma unroll
            for (int q8 = 0; q8 < 4; ++q8) {
                int o = otb + 8 * q8 + 4 * hi32;
                float4 bv = *(const float4*)(bias + o);
                h4 v = {(_Float16)(acc[4 * q8 + 0] + bv.x), (_Float16)(acc[4 * q8 + 1] + bv.y),
                        (_Float16)(acc[4 * q8 + 2] + bv.z), (_Float16)(acc[4 * q8 + 3] + bv.w)};
                *(h4*)(Kp + kp_idx(n0 + l31, o)) = v;
            }
        } else if (OUTM == 2) {
            _Float16* Vp = (_Float16*)outp;
            int o = otb + l31;
            float bc = bias[o];
            #pragma unroll
            for (int q8 = 0; q8 < 4; ++q8) {
                int n = n0 + 8 * q8 + 4 * hi32;
                h4 v = {(_Float16)(acc[4 * q8 + 0] + bc), (_Float16)(acc[4 * q8 + 1] + bc),
                        (_Float16)(acc[4 * q8 + 2] + bc), (_Float16)(acc[4 * q8 + 3] + bc)};
                *(h4*)(Vp + vp_idx(n, o)) = v;
            }
        } else {
            float* of = (float*)outp;
            #pragma unroll
            for (int r = 0; r < 16; ++r) {
                int o = otb + (r & 3) + 8 * (r >> 2) + 4 * hi32;
                of[(size_t)(b * Cd + o) * HWd + hw0 + l31] = acc[r] + bias[o];
            }
        }
    }
}

// ---------------- MFMA flash attention v12: iteration-level software pipeline ------
// v6 structure (8 waves, QBLK=64, NKS=4, packed K/V streaming) but QK(it+1) is
// hoisted into the same compute region as PV(it): per iter =
// [softmax(s_cur), 2 barriers] [V(it) loads -> QK(it+1) -> rescale -> PV(it)].
// K latency drains under PV+softmax; V latency drains under QK MFMAs.
__global__ __launch_bounds__(512, 2) void attn_v12_k(
    const _Float16* __restrict__ Qp,
    const _Float16* __restrict__ Kp,
    const _Float16* __restrict__ Vp,
    _Float16* __restrict__ partH,        // [NKS][Cd][Nd] normalized fp16
    float* __restrict__ marr,            // [NKS][Nd]
    float* __restrict__ larr) {          // [NKS][Nd]
    __shared__ _Float16 Qs[2 * 16384];   // 64KB
    __shared__ _Float16 Pl[8192];        // 16KB (single buffer; race-free, see text)
    __shared__ float tm_s[4][64], ls_s[4][64];

    const int tid = threadIdx.x;
    const int wave = tid >> 6;
    const int lane = tid & 63;
    const int l31 = lane & 31;
    const int hi32 = lane >> 5;
    const int kt = wave & 3;
    const int qg = wave >> 2;
    const int nqb = Nd / QBLK;           // 144
    const int qb = blockIdx.x % nqb;
    const int ks = blockIdx.x / nqb;
    const int q0 = qb * QBLK;
    const int kbt0 = ks * AITERS;

    {
        const _Float16* Qt = Qp + (size_t)(q0 >> 5) * 16384;
        #pragma unroll
        for (int j = 0; j < 8; ++j)
            gload_lds16(Qt + (size_t)j * 4096 + tid * 8,
                        (char*)Qs + j * 8192 + wave * 1024);
    }
    __syncthreads();

    const _Float16* qsb = Qs + qg * 16384;

    f32x16 o_acc[2][2];
    #pragma unroll
    for (int c = 0; c < 2; ++c)
        #pragma unroll
        for (int q = 0; q < 2; ++q)
            #pragma unroll
            for (int r = 0; r < 16; ++r) o_acc[c][q][r] = 0.f;
    float m0 = -INFINITY, m1 = -INFINITY, l0 = 0.f, l1 = 0.f;

    // ---- prologue: s_cur = QK(tile 0)
    f32x16 s_cur;
    #pragma unroll
    for (int r = 0; r < 16; ++r) s_cur[r] = 0.f;
    {
        const _Float16* kp = Kp + ((size_t)kbt0 * 4 + kt) * 32 * 512;
        #pragma unroll
        for (int f = 0; f < 32; ++f) {
            half8 ka = *(const half8*)(kp + (size_t)f * 512 + lane * 8);
            half8 qb8 = *(const half8*)(qsb + (2 * f + hi32) * 256 + l31 * 8);
            s_cur = __builtin_amdgcn_mfma_f32_32x32x16_f16(ka, qb8, s_cur, 0, 0, 0);
        }
    }

    for (int it = 0; it < AITERS; ++it) {
        // ---- softmax region on s_cur (tile it)
        float tmax = s_cur[0];
        #pragma unroll
        for (int r = 1; r < 16; ++r) tmax = fmaxf(tmax, s_cur[r]);
        tmax = fmaxf(tmax, __shfl_xor(tmax, 32));
        if (lane < 32) tm_s[kt][qg * 32 + lane] = tmax;
        __syncthreads();   // BAR_A: tm_s visible; prev-iter Pl/stat readers done

        float mn0 = fmaxf(fmaxf(fmaxf(tm_s[0][l31], tm_s[1][l31]),
                                fmaxf(tm_s[2][l31], tm_s[3][l31])), m0);
        float mn1 = fmaxf(fmaxf(fmaxf(tm_s[0][32 + l31], tm_s[1][32 + l31]),
                                fmaxf(tm_s[2][32 + l31], tm_s[3][32 + l31])), m1);
        float corr0 = __expf(m0 - mn0);
        float corr1 = __expf(m1 - mn1);
        float mn_own = qg ? mn1 : mn0;

        float p[16];
        float psum = 0.f;
        #pragma unroll
        for (int r = 0; r < 16; ++r) { p[r] = __expf(s_cur[r] - mn_own); psum += p[r]; }
        #pragma unroll
        for (int g = 0; g < 4; ++g) {
            h4 v = {(_Float16)p[4 * g + 0], (_Float16)p[4 * g + 1],
                    (_Float16)p[4 * g + 2], (_Float16)p[4 * g + 3]};
            *(h4*)(Pl + (qg * 8 + kt * 2 + (g >> 1)) * 512 + (g & 1) * 256
                      + l31 * 8 + 4 * hi32) = v;
        }
        psum += __shfl_xor(psum, 32);
        if (lane < 32) ls_s[kt][qg * 32 + lane] = psum;
        __syncthreads();   // BAR_B: Pl, ls_s visible

        l0 = l0 * corr0 + (ls_s[0][l31] + ls_s[1][l31]) + (ls_s[2][l31] + ls_s[3][l31]);
        l1 = l1 * corr1 + (ls_s[0][32 + l31] + ls_s[1][32 + l31])
                        + (ls_s[2][32 + l31] + ls_s[3][32 + l31]);
        m0 = mn0; m1 = mn1;

        // ---- compute region: V(it) loads, QK(it+1), rescale, PV(it)
        half8 va[16];                    // [cht*8 + kc] — issued first, consumed last
        #pragma unroll
        for (int cht = 0; cht < 2; ++cht)
            #pragma unroll
            for (int kc = 0; kc < 8; ++kc)
                va[cht * 8 + kc] = *(const half8*)(
                    Vp + (((size_t)(kbt0 + it) * 16 + wave * 2 + cht) * 8 + kc) * 512
                       + lane * 8);

        f32x16 s_next;
        #pragma unroll
        for (int r = 0; r < 16; ++r) s_next[r] = 0.f;
        if (it + 1 < AITERS) {
            const _Float16* kp = Kp + ((size_t)(kbt0 + it + 1) * 4 + kt) * 32 * 512;
            __builtin_amdgcn_s_setprio(1);
            #pragma unroll
            for (int f = 0; f < 32; ++f) {
                half8 ka = *(const half8*)(kp + (size_t)f * 512 + lane * 8);
                half8 qb8 = *(const half8*)(qsb + (2 * f + hi32) * 256 + l31 * 8);
                s_next = __builtin_amdgcn_mfma_f32_32x32x16_f16(ka, qb8, s_next, 0, 0, 0);
            }
            __builtin_amdgcn_s_setprio(0);
        }

        #pragma unroll
        for (int cht = 0; cht < 2; ++cht)
            #pragma unroll
            for (int r = 0; r < 16; ++r) {
                o_acc[cht][0][r] *= corr0;
                o_acc[cht][1][r] *= corr1;
            }

        __builtin_amdgcn_s_setprio(1);
        #pragma unroll
        for (int qt = 0; qt < 2; ++qt)
            #pragma unroll
            for (int kc = 0; kc < 8; ++kc) {
                half8 pfrag = *(const half8*)(Pl + (qt * 8 + kc) * 512
                                                 + hi32 * 256 + l31 * 8);
                #pragma unroll
                for (int cht = 0; cht < 2; ++cht)
                    o_acc[cht][qt] = __builtin_amdgcn_mfma_f32_32x32x16_f16(
                        va[cht * 8 + kc], pfrag, o_acc[cht][qt], 0, 0, 0);
            }
        __builtin_amdgcn_s_setprio(0);

        s_cur = s_next;
    }

    // ---- epilogue: NORMALIZED fp16 partials (ch-major) + (m, l)
    float li0 = 1.f / l0, li1 = 1.f / l1;
    #pragma unroll
    for (int cht = 0; cht < 2; ++cht)
        #pragma unroll
        for (int qt = 0; qt < 2; ++qt)
            #pragma unroll
            for (int r = 0; r < 16; ++r) {
                int row = (r & 3) + 8 * (r >> 2) + 4 * hi32;
                int ch = wave * 64 + cht * 32 + row;
                int q = q0 + qt * 32 + l31;
                partH[((size_t)ks * Cd + ch) * Nd + q] =
                    (_Float16)(o_acc[cht][qt][r] * (qt ? li1 : li0));
            }
    if (wave == 0 && lane < 32) {
        marr[(size_t)ks * Nd + q0 + lane] = m0;
        larr[(size_t)ks * Nd + q0 + lane] = l0;
        marr[(size_t)ks * Nd + q0 + 32 + lane] = m1;
        larr[(size_t)ks * Nd + q0 + 32 + lane] = l1;
    }
}

// ---------------- LSE merge of 4 normalized key-split partials (plane 0) ----------
__global__ __launch_bounds__(256) void merge4_k(_Float16* __restrict__ partH,
                                                const float* __restrict__ marr,
                                                const float* __restrict__ larr) {
    size_t idx = (size_t)blockIdx.x * 256 + threadIdx.x;
    if (idx >= (size_t)Cd * Nd) return;
    int q = (int)(idx % Nd);
    float mv[NKS], wv[NKS];
    float mm = -INFINITY;
    #pragma unroll
    for (int s = 0; s < NKS; ++s) { mv[s] = marr[(size_t)s * Nd + q]; mm = fmaxf(mm, mv[s]); }
    float L = 0.f;
    #pragma unroll
    for (int s = 0; s < NKS; ++s) {
        wv[s] = larr[(size_t)s * Nd + q] * __expf(mv[s] - mm);
        L += wv[s];
    }
    float val = 0.f;
    #pragma unroll
    for (int s = 0; s < NKS; ++s)
        val += wv[s] * (float)partH[(size_t)s * Cd * Nd + idx];
    partH[idx] = (_Float16)(val / L);
}

// ---------------- BN stats (per channel, double accumulation) ----------------
__global__ __launch_bounds__(256) void bnstats_k(const float* __restrict__ y,
                                                 const float* __restrict__ gamma,
                                                 const float* __restrict__ beta,
                                                 float* __restrict__ stats) {
    const int c = blockIdx.x;
    const int tid = threadIdx.x;
    double s = 0.0, sq = 0.0;
    for (int b = 0; b < Bd; ++b) {
        const float* p = y + (size_t)(b * Cd + c) * HWd;
        for (int i = tid; i < HWd; i += 256) {
            double v = (double)p[i];
            s += v;
            sq += v * v;
        }
    }
    #pragma unroll
    for (int off = 32; off; off >>= 1) {
        s  += __shfl_xor(s, off, 64);
        sq += __shfl_xor(sq, off, 64);
    }
    __shared__ double ss[4], sqs[4];
    int wid = tid >> 6;
    if ((tid & 63) == 0) { ss[wid] = s; sqs[wid] = sq; }
    __syncthreads();
    if (tid == 0) {
        double S = ss[0] + ss[1] + ss[2] + ss[3];
        double Q = sqs[0] + sqs[1] + sqs[2] + sqs[3];
        double mean = S / (double)Nd;
        double var = Q / (double)Nd - mean * mean;
        float inv = (float)(1.0 / sqrt(var + (double)BN_EPS));
        float sc = gamma[c] * inv;
        stats[c] = sc;
        stats[Cd + c] = beta[c] - (float)mean * sc;
    }
}

__global__ __launch_bounds__(256) void bnapply_k(float* __restrict__ y,
                                                 const float* __restrict__ stats) {
    int idx = blockIdx.x * 256 + threadIdx.x;
    if (idx >= Bd * Cd * HWd) return;
    int c = (idx / HWd) % Cd;
    float v = fmaf(y[idx], stats[c], stats[Cd + c]);
    y[idx] = fmaxf(v, 0.f);
}

extern "C" void kernel_launch(void* const* d_in, const int* in_sizes, int n_in,
                              void* d_out, int out_size, void* d_ws, size_t ws_size,
                              hipStream_t stream) {
    const float* x     = (const float*)d_in[0];
    const float* depth = (const float*)d_in[1];
    const float* w_rgb = (const float*)d_in[2];
    const float* b_rgb = (const float*)d_in[3];
    const float* w_lhs = (const float*)d_in[4];
    const float* b_lhs = (const float*)d_in[5];
    const float* w_rhs = (const float*)d_in[6];
    const float* b_rhs = (const float*)d_in[7];
    const float* w_dec = (const float*)d_in[8];
    const float* b_dec = (const float*)d_in[9];
    const float* gamma = (const float*)d_in[10];
    const float* beta  = (const float*)d_in[11];
    float* out = (float*)d_out;

    char* wsb = (char*)d_ws;
    const size_t NC = (size_t)Nd * Cd;
    _Float16* Qp    = (_Float16*)wsb;
    _Float16* Kp    = (_Float16*)(wsb + NC * 2);
    _Float16* Vp    = (_Float16*)(wsb + NC * 4);
    _Float16* partH = (_Float16*)(wsb + NC * 6);
    float* marr  = (float*)(wsb + NC * 6 + (size_t)NKS * NC * 2);
    float* larr  = marr + (size_t)NKS * Nd;
    float* stats = larr + (size_t)NKS * Nd;
    _Float16* wpLhs = (_Float16*)(stats + 2 * Cd);
    _Float16* wpRhs = wpLhs + (size_t)Cd * Cd;
    _Float16* wpRgb = wpRhs + (size_t)Cd * Cd;
    _Float16* wpDec = wpRgb + (size_t)Cd * Cd;

    wpack_k<<<dim3(128, 4), 256, 0, stream>>>(w_lhs, w_rhs, w_rgb, w_dec,
                                              wpLhs, wpRhs, wpRgb, wpDec);

    dim3 gLin(Nd / 32, 2);
    linproj_k<0, 0><<<gLin, 256, 0, stream>>>(depth, wpLhs, b_lhs, Qp);
    linproj_k<0, 1><<<gLin, 256, 0, stream>>>(depth, wpRhs, b_rhs, Kp);
    linproj_k<0, 2><<<gLin, 256, 0, stream>>>(x, wpRgb, b_rgb, Vp);

    attn_v12_k<<<(Nd / QBLK) * NKS, 512, 0, stream>>>(Qp, Kp, Vp, partH, marr, larr);

    merge4_k<<<(int)((NC + 255) / 256), 256, 0, stream>>>(partH, marr, larr);

    // decoder reads merged fp16 ch-major (partH plane 0), writes f32 BCHW to d_out
    linproj_k<3, 3><<<gLin, 256, 0, stream>>>(partH, wpDec, b_dec, out);

    bnstats_k<<<Cd, 256, 0, stream>>>(out, gamma, beta, stats);
    bnapply_k<<<(Bd * Cd * HWd + 255) / 256, 256, 0, stream>>>(out, stats);
}

// Round 16
// 371.548 us; speedup vs baseline: 1.2623x; 1.2623x over previous
//
#include <hip/hip_runtime.h>
#include <math.h>

#define Bd 4
#define Cd 512
#define Hd 48
#define Wd 48
#define HWd (Hd * Wd)          // 2304
#define Nd (Bd * HWd)          // 9216
#define BN_EPS 1e-5f

#define QBLK 64
#define KBLK 128
#define NKS 4
#define KSLEN (Nd / NKS)       // 2304
#define AITERS (KSLEN / KBLK)  // 18

typedef _Float16 half8 __attribute__((ext_vector_type(8)));
typedef _Float16 h4 __attribute__((ext_vector_type(4)));
typedef float f32x16 __attribute__((ext_vector_type(16)));

__device__ inline void gload_lds16(const void* g, void* l) {
    __builtin_amdgcn_global_load_lds((const __attribute__((address_space(1))) void*)g,
                                     (__attribute__((address_space(3))) void*)l, 16, 0, 0);
}

// ---- shared packed-layout index functions, writer==reader ----
__device__ inline size_t wp_idx(int o, int c) {
    return (((size_t)(o >> 5) * 32 + (c >> 4)) * 64 + ((o & 31) + 32 * ((c >> 3) & 1))) * 8 + (c & 7);
}
__device__ inline size_t qp_idx(int q, int c) {
    return (((size_t)(q >> 5) * 64 + (c >> 3)) * 32 + (q & 31)) * 8 + (c & 7);
}
__device__ inline size_t kp_idx(int n, int o) {
    return ((((size_t)(n >> 7) * 4 + ((n >> 5) & 3)) * 32 + (o >> 4)) * 64
            + ((n & 31) + 32 * ((o >> 3) & 1))) * 8 + (o & 7);
}
__device__ inline size_t vp_idx(int n, int o) {
    return ((((size_t)(n >> 7) * 16 + (o >> 5)) * 8 + ((n >> 4) & 7)) * 64
            + ((o & 31) + 32 * ((n >> 3) & 1))) * 8 + (n & 7);
}

// ---------------- weight pack: f32 [512][512] -> fp16 fragment order ----------------
__global__ __launch_bounds__(256) void wpack_k(const float* __restrict__ w0,
                                               const float* __restrict__ w1,
                                               const float* __restrict__ w2,
                                               const float* __restrict__ w3,
                                               _Float16* __restrict__ p0,
                                               _Float16* __restrict__ p1,
                                               _Float16* __restrict__ p2,
                                               _Float16* __restrict__ p3) {
    const float* w; _Float16* p;
    switch (blockIdx.y) {
        case 0: w = w0; p = p0; break;
        case 1: w = w1; p = p1; break;
        case 2: w = w2; p = p2; break;
        default: w = w3; p = p3; break;
    }
    int idx = blockIdx.x * 256 + threadIdx.x;
    int o = idx >> 6;
    int cc = (idx & 63) * 8;
    float4 a = *(const float4*)(w + (size_t)o * 512 + cc);
    float4 b = *(const float4*)(w + (size_t)o * 512 + cc + 4);
    half8 v = {(_Float16)a.x, (_Float16)a.y, (_Float16)a.z, (_Float16)a.w,
               (_Float16)b.x, (_Float16)b.y, (_Float16)b.z, (_Float16)b.w};
    *(half8*)(p + wp_idx(o, cc)) = v;
}

// ---------------- MFMA linear (1x1 conv): 32-token tile, 256-o half ----------------
template<int INM, int OUTM>
__global__ __launch_bounds__(256, 2) void linproj_k(const void* __restrict__ in,
                                                    const _Float16* __restrict__ Wp,
                                                    const float* __restrict__ bias,
                                                    void* __restrict__ outp) {
    constexpr bool SWAP = (OUTM == 2);
    __shared__ _Float16 Xs[16384];

    const int tid = threadIdx.x;
    const int wave = tid >> 6;
    const int lane = tid & 63;
    const int l31 = lane & 31;
    const int hi32 = lane >> 5;
    const int n0 = blockIdx.x * 32;
    const int by = blockIdx.y;
    const int b = n0 / HWd;
    const int hw0 = n0 % HWd;

    {
        const int t = tid & 31;
        const int c0 = tid >> 5;
        #pragma unroll 8
        for (int k = 0; k < 64; ++k) {
            int c = c0 + 8 * k;
            float val;
            if (INM == 0)
                val = ((const float*)in)[(size_t)(b * Cd + c) * HWd + hw0 + t];
            else
                val = (float)((const _Float16*)in)[(size_t)c * Nd + n0 + t];
            if (!SWAP)
                Xs[(c >> 3) * 256 + t * 8 + (c & 7)] = (_Float16)val;
            else
                Xs[(c >> 4) * 512 + (t + 32 * ((c >> 3) & 1)) * 8 + (c & 7)] = (_Float16)val;
        }
    }
    __syncthreads();

    #pragma unroll
    for (int ot = 0; ot < 2; ++ot) {
        const int otb = by * 256 + ot * 128 + wave * 32;

        half8 wa[32];
        const _Float16* wpb = Wp + ((size_t)(otb >> 5) * 32) * 512;
        #pragma unroll
        for (int f = 0; f < 32; ++f)
            wa[f] = *(const half8*)(wpb + (size_t)f * 512 + lane * 8);

        f32x16 acc;
        #pragma unroll
        for (int r = 0; r < 16; ++r) acc[r] = 0.f;

        __builtin_amdgcn_s_setprio(1);
        #pragma unroll
        for (int f = 0; f < 32; ++f) {
            if (!SWAP) {
                half8 xb = *(const half8*)(Xs + (2 * f + hi32) * 256 + l31 * 8);
                acc = __builtin_amdgcn_mfma_f32_32x32x16_f16(wa[f], xb, acc, 0, 0, 0);
            } else {
                half8 xa = *(const half8*)(Xs + f * 512 + lane * 8);
                acc = __builtin_amdgcn_mfma_f32_32x32x16_f16(xa, wa[f], acc, 0, 0, 0);
            }
        }
        __builtin_amdgcn_s_setprio(0);

        if (OUTM == 0) {
            _Float16* Qp = (_Float16*)outp;
            #pragma unroll
            for (int q8 = 0; q8 < 4; ++q8) {
                int o = otb + 8 * q8 + 4 * hi32;
                float4 bv = *(const float4*)(bias + o);
                h4 v = {(_Float16)(acc[4 * q8 + 0] + bv.x), (_Float16)(acc[4 * q8 + 1] + bv.y),
                        (_Float16)(acc[4 * q8 + 2] + bv.z), (_Float16)(acc[4 * q8 + 3] + bv.w)};
                *(h4*)(Qp + qp_idx(n0 + l31, o)) = v;
            }
        } else if (OUTM == 1) {
            _Float16* Kp = (_Float16*)outp;
            #pragma unroll
            for (int q8 = 0; q8 < 4; ++q8) {
                int o = otb + 8 * q8 + 4 * hi32;
                float4 bv = *(const float4*)(bias + o);
                h4 v = {(_Float16)(acc[4 * q8 + 0] + bv.x), (_Float16)(acc[4 * q8 + 1] + bv.y),
                        (_Float16)(acc[4 * q8 + 2] + bv.z), (_Float16)(acc[4 * q8 + 3] + bv.w)};
                *(h4*)(Kp + kp_idx(n0 + l31, o)) = v;
            }
        } else if (OUTM == 2) {
            _Float16* Vp = (_Float16*)outp;
            int o = otb + l31;
            float bc = bias[o];
            #pragma unroll
            for (int q8 = 0; q8 < 4; ++q8) {
                int n = n0 + 8 * q8 + 4 * hi32;
                h4 v = {(_Float16)(acc[4 * q8 + 0] + bc), (_Float16)(acc[4 * q8 + 1] + bc),
                        (_Float16)(acc[4 * q8 + 2] + bc), (_Float16)(acc[4 * q8 + 3] + bc)};
                *(h4*)(Vp + vp_idx(n, o)) = v;
            }
        } else {
            float* of = (float*)outp;
            #pragma unroll
            for (int r = 0; r < 16; ++r) {
                int o = otb + (r & 3) + 8 * (r >> 2) + 4 * hi32;
                of[(size_t)(b * Cd + o) * HWd + hw0 + l31] = acc[r] + bias[o];
            }
        }
    }
}

// ---------------- MFMA flash attention v6: QBLK=64, 8 waves, packed streaming ------
// wave = (kt = wave&3 key sub-tile, qg = wave>>2 q sub-tile). Q in LDS (64KB),
// K/V reg-streamed from packed global, P via 16KB LDS (single buffer, 2 barriers).
// Each wave tracks softmax state (m,l) for BOTH q-tiles in scalars.
__global__ __launch_bounds__(512, 2) void attn_v6_k(
    const _Float16* __restrict__ Qp,
    const _Float16* __restrict__ Kp,
    const _Float16* __restrict__ Vp,
    _Float16* __restrict__ partH,        // [NKS][Cd][Nd] normalized fp16
    float* __restrict__ marr,            // [NKS][Nd]
    float* __restrict__ larr) {          // [NKS][Nd]
    __shared__ _Float16 Qs[2 * 16384];   // 64KB: [qt][chunk64][q32][8]
    __shared__ _Float16 Pl[8192];        // 16KB: [qt2][kc8][sub2][q32][e8]
    __shared__ float tm_s[4][64], ls_s[4][64];

    const int tid = threadIdx.x;
    const int wave = tid >> 6;
    const int lane = tid & 63;
    const int l31 = lane & 31;
    const int hi32 = lane >> 5;
    const int kt = wave & 3;
    const int qg = wave >> 2;
    const int nqb = Nd / QBLK;           // 144
    const int qb = blockIdx.x % nqb;
    const int ks = blockIdx.x / nqb;
    const int q0 = qb * QBLK;
    const int kbt0 = ks * AITERS;

    // ---- stage Q (64KB contiguous from Q-pack; two 32-q tiles)
    {
        const _Float16* Qt = Qp + (size_t)(q0 >> 5) * 16384;
        #pragma unroll
        for (int j = 0; j < 8; ++j)
            gload_lds16(Qt + (size_t)j * 4096 + tid * 8,
                        (char*)Qs + j * 8192 + wave * 1024);
    }
    __syncthreads();

    f32x16 o_acc[2][2];                  // [cht][qt]
    #pragma unroll
    for (int c = 0; c < 2; ++c)
        #pragma unroll
        for (int q = 0; q < 2; ++q)
            #pragma unroll
            for (int r = 0; r < 16; ++r) o_acc[c][q][r] = 0.f;
    float m0 = -INFINITY, m1 = -INFINITY, l0 = 0.f, l1 = 0.f;

    for (int it = 0; it < AITERS; ++it) {
        // ---- QK^T: this wave's 32-key tile x its q-tile, 32 MFMAs over d=512
        const _Float16* kp = Kp + ((size_t)(kbt0 + it) * 4 + kt) * 32 * 512;
        half8 ka[32];
        #pragma unroll
        for (int f = 0; f < 32; ++f)
            ka[f] = *(const half8*)(kp + (size_t)f * 512 + lane * 8);

        f32x16 s;
        #pragma unroll
        for (int r = 0; r < 16; ++r) s[r] = 0.f;
        const _Float16* qsb = Qs + qg * 16384;
        __builtin_amdgcn_s_setprio(1);
        #pragma unroll
        for (int f = 0; f < 32; ++f) {
            half8 qb8 = *(const half8*)(qsb + (2 * f + hi32) * 256 + l31 * 8);
            s = __builtin_amdgcn_mfma_f32_32x32x16_f16(ka[f], qb8, s, 0, 0, 0);
        }
        __builtin_amdgcn_s_setprio(0);

        float tmax = s[0];
        #pragma unroll
        for (int r = 1; r < 16; ++r) tmax = fmaxf(tmax, s[r]);
        tmax = fmaxf(tmax, __shfl_xor(tmax, 32));
        if (lane < 32) tm_s[kt][qg * 32 + lane] = tmax;
        __syncthreads();   // BAR1: tm_s visible; prev-iter Pl reads drained

        // new maxes for BOTH q-tiles (per-lane q = l31 within each tile)
        float mn0 = fmaxf(fmaxf(fmaxf(tm_s[0][l31], tm_s[1][l31]),
                                fmaxf(tm_s[2][l31], tm_s[3][l31])), m0);
        float mn1 = fmaxf(fmaxf(fmaxf(tm_s[0][32 + l31], tm_s[1][32 + l31]),
                                fmaxf(tm_s[2][32 + l31], tm_s[3][32 + l31])), m1);
        float corr0 = __expf(m0 - mn0);
        float corr1 = __expf(m1 - mn1);
        float mn_own = qg ? mn1 : mn0;

        // ---- P = exp(s - mn_own) -> Pl (own tile), psum
        float p[16];
        float psum = 0.f;
        #pragma unroll
        for (int r = 0; r < 16; ++r) { p[r] = __expf(s[r] - mn_own); psum += p[r]; }
        #pragma unroll
        for (int g = 0; g < 4; ++g) {
            h4 v = {(_Float16)p[4 * g + 0], (_Float16)p[4 * g + 1],
                    (_Float16)p[4 * g + 2], (_Float16)p[4 * g + 3]};
            *(h4*)(Pl + (qg * 8 + kt * 2 + (g >> 1)) * 512 + (g & 1) * 256
                      + l31 * 8 + 4 * hi32) = v;
        }
        psum += __shfl_xor(psum, 32);
        if (lane < 32) ls_s[kt][qg * 32 + lane] = psum;
        __syncthreads();   // BAR2: Pl, ls_s visible

        l0 = l0 * corr0 + (ls_s[0][l31] + ls_s[1][l31]) + (ls_s[2][l31] + ls_s[3][l31]);
        l1 = l1 * corr1 + (ls_s[0][32 + l31] + ls_s[1][32 + l31])
                        + (ls_s[2][32 + l31] + ls_s[3][32 + l31]);
        m0 = mn0; m1 = mn1;

        // ---- V loads: this wave's 64-ch slice (2 chg groups), all 128 keys
        half8 va[16];                    // [cht*8 + kc]
        #pragma unroll
        for (int cht = 0; cht < 2; ++cht)
            #pragma unroll
            for (int kc = 0; kc < 8; ++kc)
                va[cht * 8 + kc] = *(const half8*)(
                    Vp + (((size_t)(kbt0 + it) * 16 + wave * 2 + cht) * 8 + kc) * 512
                       + lane * 8);

        // ---- rescale O, then PV: 32 MFMAs
        #pragma unroll
        for (int cht = 0; cht < 2; ++cht)
            #pragma unroll
            for (int r = 0; r < 16; ++r) {
                o_acc[cht][0][r] *= corr0;
                o_acc[cht][1][r] *= corr1;
            }

        __builtin_amdgcn_s_setprio(1);
        #pragma unroll
        for (int qt = 0; qt < 2; ++qt)
            #pragma unroll
            for (int kc = 0; kc < 8; ++kc) {
                half8 pfrag = *(const half8*)(Pl + (qt * 8 + kc) * 512
                                                 + hi32 * 256 + l31 * 8);
                #pragma unroll
                for (int cht = 0; cht < 2; ++cht)
                    o_acc[cht][qt] = __builtin_amdgcn_mfma_f32_32x32x16_f16(
                        va[cht * 8 + kc], pfrag, o_acc[cht][qt], 0, 0, 0);
            }
        __builtin_amdgcn_s_setprio(0);
    }

    // ---- epilogue: NORMALIZED fp16 partials (ch-major) + (m, l)
    float li0 = 1.f / l0, li1 = 1.f / l1;
    #pragma unroll
    for (int cht = 0; cht < 2; ++cht)
        #pragma unroll
        for (int qt = 0; qt < 2; ++qt)
            #pragma unroll
            for (int r = 0; r < 16; ++r) {
                int row = (r & 3) + 8 * (r >> 2) + 4 * hi32;
                int ch = wave * 64 + cht * 32 + row;
                int q = q0 + qt * 32 + l31;
                partH[((size_t)ks * Cd + ch) * Nd + q] =
                    (_Float16)(o_acc[cht][qt][r] * (qt ? li1 : li0));
            }
    if (wave == 0 && lane < 32) {
        marr[(size_t)ks * Nd + q0 + lane] = m0;
        larr[(size_t)ks * Nd + q0 + lane] = l0;
        marr[(size_t)ks * Nd + q0 + 32 + lane] = m1;
        larr[(size_t)ks * Nd + q0 + 32 + lane] = l1;
    }
}

// ---------------- LSE merge of 4 normalized key-split partials (plane 0) ----------
__global__ __launch_bounds__(256) void merge4_k(_Float16* __restrict__ partH,
                                                const float* __restrict__ marr,
                                                const float* __restrict__ larr) {
    size_t idx = (size_t)blockIdx.x * 256 + threadIdx.x;
    if (idx >= (size_t)Cd * Nd) return;
    int q = (int)(idx % Nd);
    float mv[NKS], wv[NKS];
    float mm = -INFINITY;
    #pragma unroll
    for (int s = 0; s < NKS; ++s) { mv[s] = marr[(size_t)s * Nd + q]; mm = fmaxf(mm, mv[s]); }
    float L = 0.f;
    #pragma unroll
    for (int s = 0; s < NKS; ++s) {
        wv[s] = larr[(size_t)s * Nd + q] * __expf(mv[s] - mm);
        L += wv[s];
    }
    float val = 0.f;
    #pragma unroll
    for (int s = 0; s < NKS; ++s)
        val += wv[s] * (float)partH[(size_t)s * Cd * Nd + idx];
    partH[idx] = (_Float16)(val / L);
}

// ---------------- BN stats (per channel, double accumulation) ----------------
__global__ __launch_bounds__(256) void bnstats_k(const float* __restrict__ y,
                                                 const float* __restrict__ gamma,
                                                 const float* __restrict__ beta,
                                                 float* __restrict__ stats) {
    const int c = blockIdx.x;
    const int tid = threadIdx.x;
    double s = 0.0, sq = 0.0;
    for (int b = 0; b < Bd; ++b) {
        const float* p = y + (size_t)(b * Cd + c) * HWd;
        for (int i = tid; i < HWd; i += 256) {
            double v = (double)p[i];
            s += v;
            sq += v * v;
        }
    }
    #pragma unroll
    for (int off = 32; off; off >>= 1) {
        s  += __shfl_xor(s, off, 64);
        sq += __shfl_xor(sq, off, 64);
    }
    __shared__ double ss[4], sqs[4];
    int wid = tid >> 6;
    if ((tid & 63) == 0) { ss[wid] = s; sqs[wid] = sq; }
    __syncthreads();
    if (tid == 0) {
        double S = ss[0] + ss[1] + ss[2] + ss[3];
        double Q = sqs[0] + sqs[1] + sqs[2] + sqs[3];
        double mean = S / (double)Nd;
        double var = Q / (double)Nd - mean * mean;
        float inv = (float)(1.0 / sqrt(var + (double)BN_EPS));
        float sc = gamma[c] * inv;
        stats[c] = sc;
        stats[Cd + c] = beta[c] - (float)mean * sc;
    }
}

__global__ __launch_bounds__(256) void bnapply_k(float* __restrict__ y,
                                                 const float* __restrict__ stats) {
    int idx = blockIdx.x * 256 + threadIdx.x;
    if (idx >= Bd * Cd * HWd) return;
    int c = (idx / HWd) % Cd;
    float v = fmaf(y[idx], stats[c], stats[Cd + c]);
    y[idx] = fmaxf(v, 0.f);
}

extern "C" void kernel_launch(void* const* d_in, const int* in_sizes, int n_in,
                              void* d_out, int out_size, void* d_ws, size_t ws_size,
                              hipStream_t stream) {
    const float* x     = (const float*)d_in[0];
    const float* depth = (const float*)d_in[1];
    const float* w_rgb = (const float*)d_in[2];
    const float* b_rgb = (const float*)d_in[3];
    const float* w_lhs = (const float*)d_in[4];
    const float* b_lhs = (const float*)d_in[5];
    const float* w_rhs = (const float*)d_in[6];
    const float* b_rhs = (const float*)d_in[7];
    const float* w_dec = (const float*)d_in[8];
    const float* b_dec = (const float*)d_in[9];
    const float* gamma = (const float*)d_in[10];
    const float* beta  = (const float*)d_in[11];
    float* out = (float*)d_out;

    char* wsb = (char*)d_ws;
    const size_t NC = (size_t)Nd * Cd;
    _Float16* Qp    = (_Float16*)wsb;
    _Float16* Kp    = (_Float16*)(wsb + NC * 2);
    _Float16* Vp    = (_Float16*)(wsb + NC * 4);
    _Float16* partH = (_Float16*)(wsb + NC * 6);
    float* marr  = (float*)(wsb + NC * 6 + (size_t)NKS * NC * 2);
    float* larr  = marr + (size_t)NKS * Nd;
    float* stats = larr + (size_t)NKS * Nd;
    _Float16* wpLhs = (_Float16*)(stats + 2 * Cd);
    _Float16* wpRhs = wpLhs + (size_t)Cd * Cd;
    _Float16* wpRgb = wpRhs + (size_t)Cd * Cd;
    _Float16* wpDec = wpRgb + (size_t)Cd * Cd;

    wpack_k<<<dim3(128, 4), 256, 0, stream>>>(w_lhs, w_rhs, w_rgb, w_dec,
                                              wpLhs, wpRhs, wpRgb, wpDec);

    dim3 gLin(Nd / 32, 2);
    linproj_k<0, 0><<<gLin, 256, 0, stream>>>(depth, wpLhs, b_lhs, Qp);
    linproj_k<0, 1><<<gLin, 256, 0, stream>>>(depth, wpRhs, b_rhs, Kp);
    linproj_k<0, 2><<<gLin, 256, 0, stream>>>(x, wpRgb, b_rgb, Vp);

    attn_v6_k<<<(Nd / QBLK) * NKS, 512, 0, stream>>>(Qp, Kp, Vp, partH, marr, larr);

    merge4_k<<<(int)((NC + 255) / 256), 256, 0, stream>>>(partH, marr, larr);

    linproj_k<3, 3><<<gLin, 256, 0, stream>>>(partH, wpDec, b_dec, out);

    bnstats_k<<<Cd, 256, 0, stream>>>(out, gamma, beta, stats);
    bnapply_k<<<(Bd * Cd * HWd + 255) / 256, 256, 0, stream>>>(out, stats);
}

// Round 17
// 369.768 us; speedup vs baseline: 1.2684x; 1.0048x over previous
//
#include <hip/hip_runtime.h>
#include <math.h>

#define Bd 4
#define Cd 512
#define Hd 48
#define Wd 48
#define HWd (Hd * Wd)          // 2304
#define Nd (Bd * HWd)          // 9216
#define BN_EPS 1e-5f

#define QBLK 64
#define KBLK 128
#define NKS 4
#define KSLEN (Nd / NKS)       // 2304
#define AITERS (KSLEN / KBLK)  // 18

typedef _Float16 half8 __attribute__((ext_vector_type(8)));
typedef _Float16 h4 __attribute__((ext_vector_type(4)));
typedef float f32x16 __attribute__((ext_vector_type(16)));

__device__ inline void gload_lds16(const void* g, void* l) {
    __builtin_amdgcn_global_load_lds((const __attribute__((address_space(1))) void*)g,
                                     (__attribute__((address_space(3))) void*)l, 16, 0, 0);
}

// ---- shared packed-layout index functions, writer==reader ----
__device__ inline size_t wp_idx(int o, int c) {
    return (((size_t)(o >> 5) * 32 + (c >> 4)) * 64 + ((o & 31) + 32 * ((c >> 3) & 1))) * 8 + (c & 7);
}
__device__ inline size_t qp_idx(int q, int c) {
    return (((size_t)(q >> 5) * 64 + (c >> 3)) * 32 + (q & 31)) * 8 + (c & 7);
}
__device__ inline size_t kp_idx(int n, int o) {
    return ((((size_t)(n >> 7) * 4 + ((n >> 5) & 3)) * 32 + (o >> 4)) * 64
            + ((n & 31) + 32 * ((o >> 3) & 1))) * 8 + (o & 7);
}
__device__ inline size_t vp_idx(int n, int o) {
    return ((((size_t)(n >> 7) * 16 + (o >> 5)) * 8 + ((n >> 4) & 7)) * 64
            + ((o & 31) + 32 * ((n >> 3) & 1))) * 8 + (n & 7);
}

// ---------------- weight pack: f32 [512][512] -> fp16 fragment order ----------------
__global__ __launch_bounds__(256) void wpack_k(const float* __restrict__ w0,
                                               const float* __restrict__ w1,
                                               const float* __restrict__ w2,
                                               const float* __restrict__ w3,
                                               _Float16* __restrict__ p0,
                                               _Float16* __restrict__ p1,
                                               _Float16* __restrict__ p2,
                                               _Float16* __restrict__ p3) {
    const float* w; _Float16* p;
    switch (blockIdx.y) {
        case 0: w = w0; p = p0; break;
        case 1: w = w1; p = p1; break;
        case 2: w = w2; p = p2; break;
        default: w = w3; p = p3; break;
    }
    int idx = blockIdx.x * 256 + threadIdx.x;
    int o = idx >> 6;
    int cc = (idx & 63) * 8;
    float4 a = *(const float4*)(w + (size_t)o * 512 + cc);
    float4 b = *(const float4*)(w + (size_t)o * 512 + cc + 4);
    half8 v = {(_Float16)a.x, (_Float16)a.y, (_Float16)a.z, (_Float16)a.w,
               (_Float16)b.x, (_Float16)b.y, (_Float16)b.z, (_Float16)b.w};
    *(half8*)(p + wp_idx(o, cc)) = v;
}

// ---------------- MFMA linear (1x1 conv): 32-token tile, 256-o half ----------------
// INM: 0 = f32 BCHW input. OUTM: 0 = Q-pack, 1 = K-pack, 2 = V-pack (swapped)
template<int INM, int OUTM>
__global__ __launch_bounds__(256, 2) void linproj_k(const void* __restrict__ in,
                                                    const _Float16* __restrict__ Wp,
                                                    const float* __restrict__ bias,
                                                    void* __restrict__ outp) {
    constexpr bool SWAP = (OUTM == 2);
    __shared__ _Float16 Xs[16384];

    const int tid = threadIdx.x;
    const int wave = tid >> 6;
    const int lane = tid & 63;
    const int l31 = lane & 31;
    const int hi32 = lane >> 5;
    const int n0 = blockIdx.x * 32;
    const int by = blockIdx.y;
    const int b = n0 / HWd;
    const int hw0 = n0 % HWd;

    {
        const int t = tid & 31;
        const int c0 = tid >> 5;
        #pragma unroll 8
        for (int k = 0; k < 64; ++k) {
            int c = c0 + 8 * k;
            float val = ((const float*)in)[(size_t)(b * Cd + c) * HWd + hw0 + t];
            if (!SWAP)
                Xs[(c >> 3) * 256 + t * 8 + (c & 7)] = (_Float16)val;
            else
                Xs[(c >> 4) * 512 + (t + 32 * ((c >> 3) & 1)) * 8 + (c & 7)] = (_Float16)val;
        }
    }
    __syncthreads();

    #pragma unroll
    for (int ot = 0; ot < 2; ++ot) {
        const int otb = by * 256 + ot * 128 + wave * 32;

        half8 wa[32];
        const _Float16* wpb = Wp + ((size_t)(otb >> 5) * 32) * 512;
        #pragma unroll
        for (int f = 0; f < 32; ++f)
            wa[f] = *(const half8*)(wpb + (size_t)f * 512 + lane * 8);

        f32x16 acc;
        #pragma unroll
        for (int r = 0; r < 16; ++r) acc[r] = 0.f;

        __builtin_amdgcn_s_setprio(1);
        #pragma unroll
        for (int f = 0; f < 32; ++f) {
            if (!SWAP) {
                half8 xb = *(const half8*)(Xs + (2 * f + hi32) * 256 + l31 * 8);
                acc = __builtin_amdgcn_mfma_f32_32x32x16_f16(wa[f], xb, acc, 0, 0, 0);
            } else {
                half8 xa = *(const half8*)(Xs + f * 512 + lane * 8);
                acc = __builtin_amdgcn_mfma_f32_32x32x16_f16(xa, wa[f], acc, 0, 0, 0);
            }
        }
        __builtin_amdgcn_s_setprio(0);

        if (OUTM == 0) {
            _Float16* Qp = (_Float16*)outp;
            #pragma unroll
            for (int q8 = 0; q8 < 4; ++q8) {
                int o = otb + 8 * q8 + 4 * hi32;
                float4 bv = *(const float4*)(bias + o);
                h4 v = {(_Float16)(acc[4 * q8 + 0] + bv.x), (_Float16)(acc[4 * q8 + 1] + bv.y),
                        (_Float16)(acc[4 * q8 + 2] + bv.z), (_Float16)(acc[4 * q8 + 3] + bv.w)};
                *(h4*)(Qp + qp_idx(n0 + l31, o)) = v;
            }
        } else if (OUTM == 1) {
            _Float16* Kp = (_Float16*)outp;
            #pragma unroll
            for (int q8 = 0; q8 < 4; ++q8) {
                int o = otb + 8 * q8 + 4 * hi32;
                float4 bv = *(const float4*)(bias + o);
                h4 v = {(_Float16)(acc[4 * q8 + 0] + bv.x), (_Float16)(acc[4 * q8 + 1] + bv.y),
                        (_Float16)(acc[4 * q8 + 2] + bv.z), (_Float16)(acc[4 * q8 + 3] + bv.w)};
                *(h4*)(Kp + kp_idx(n0 + l31, o)) = v;
            }
        } else {
            _Float16* Vp = (_Float16*)outp;
            int o = otb + l31;
            float bc = bias[o];
            #pragma unroll
            for (int q8 = 0; q8 < 4; ++q8) {
                int n = n0 + 8 * q8 + 4 * hi32;
                h4 v = {(_Float16)(acc[4 * q8 + 0] + bc), (_Float16)(acc[4 * q8 + 1] + bc),
                        (_Float16)(acc[4 * q8 + 2] + bc), (_Float16)(acc[4 * q8 + 3] + bc)};
                *(h4*)(Vp + vp_idx(n, o)) = v;
            }
        }
    }
}

// ---------------- decoder with FUSED LSE-merge staging ----------------------------
// Reads the 4 normalized fp16 partial planes + (m,l); per staging thread n is
// fixed, so the 4 LSE weights are computed once and the merge happens inline
// while filling Xs. Replaces the separate wprep + merge4 passes entirely.
__global__ __launch_bounds__(256, 2) void lindec_k(const _Float16* __restrict__ partH,
                                                   const float* __restrict__ marr,
                                                   const float* __restrict__ larr,
                                                   const _Float16* __restrict__ Wp,
                                                   const float* __restrict__ bias,
                                                   float* __restrict__ out) {
    __shared__ _Float16 Xs[16384];

    const int tid = threadIdx.x;
    const int wave = tid >> 6;
    const int lane = tid & 63;
    const int l31 = lane & 31;
    const int hi32 = lane >> 5;
    const int n0 = blockIdx.x * 32;
    const int by = blockIdx.y;
    const int b = n0 / HWd;
    const int hw0 = n0 % HWd;
    const size_t CN = (size_t)Cd * Nd;

    {
        const int t = tid & 31;
        const int c0 = tid >> 5;
        const int n = n0 + t;
        // LSE weights for this thread's token (normalized incl. 1/L)
        float mv0 = marr[n],          mv1 = marr[Nd + n];
        float mv2 = marr[2 * Nd + n], mv3 = marr[3 * Nd + n];
        float mm = fmaxf(fmaxf(mv0, mv1), fmaxf(mv2, mv3));
        float w0 = larr[n] * __expf(mv0 - mm);
        float w1 = larr[Nd + n] * __expf(mv1 - mm);
        float w2 = larr[2 * Nd + n] * __expf(mv2 - mm);
        float w3 = larr[3 * Nd + n] * __expf(mv3 - mm);
        float inv = 1.f / (w0 + w1 + w2 + w3);
        w0 *= inv; w1 *= inv; w2 *= inv; w3 *= inv;

        #pragma unroll 8
        for (int k = 0; k < 64; ++k) {
            int c = c0 + 8 * k;
            size_t base = (size_t)c * Nd + n;
            float val = w0 * (float)partH[base]
                      + w1 * (float)partH[CN + base]
                      + w2 * (float)partH[2 * CN + base]
                      + w3 * (float)partH[3 * CN + base];
            Xs[(c >> 3) * 256 + t * 8 + (c & 7)] = (_Float16)val;
        }
    }
    __syncthreads();

    #pragma unroll
    for (int ot = 0; ot < 2; ++ot) {
        const int otb = by * 256 + ot * 128 + wave * 32;

        half8 wa[32];
        const _Float16* wpb = Wp + ((size_t)(otb >> 5) * 32) * 512;
        #pragma unroll
        for (int f = 0; f < 32; ++f)
            wa[f] = *(const half8*)(wpb + (size_t)f * 512 + lane * 8);

        f32x16 acc;
        #pragma unroll
        for (int r = 0; r < 16; ++r) acc[r] = 0.f;

        __builtin_amdgcn_s_setprio(1);
        #pragma unroll
        for (int f = 0; f < 32; ++f) {
            half8 xb = *(const half8*)(Xs + (2 * f + hi32) * 256 + l31 * 8);
            acc = __builtin_amdgcn_mfma_f32_32x32x16_f16(wa[f], xb, acc, 0, 0, 0);
        }
        __builtin_amdgcn_s_setprio(0);

        #pragma unroll
        for (int r = 0; r < 16; ++r) {
            int o = otb + (r & 3) + 8 * (r >> 2) + 4 * hi32;
            out[(size_t)(b * Cd + o) * HWd + hw0 + l31] = acc[r] + bias[o];
        }
    }
}

// ---------------- MFMA flash attention v6: QBLK=64, 8 waves, packed streaming ------
__global__ __launch_bounds__(512, 2) void attn_v6_k(
    const _Float16* __restrict__ Qp,
    const _Float16* __restrict__ Kp,
    const _Float16* __restrict__ Vp,
    _Float16* __restrict__ partH,        // [NKS][Cd][Nd] normalized fp16
    float* __restrict__ marr,            // [NKS][Nd]
    float* __restrict__ larr) {          // [NKS][Nd]
    __shared__ _Float16 Qs[2 * 16384];   // 64KB: [qt][chunk64][q32][8]
    __shared__ _Float16 Pl[8192];        // 16KB: [qt2][kc8][sub2][q32][e8]
    __shared__ float tm_s[4][64], ls_s[4][64];

    const int tid = threadIdx.x;
    const int wave = tid >> 6;
    const int lane = tid & 63;
    const int l31 = lane & 31;
    const int hi32 = lane >> 5;
    const int kt = wave & 3;
    const int qg = wave >> 2;
    const int nqb = Nd / QBLK;           // 144
    const int qb = blockIdx.x % nqb;
    const int ks = blockIdx.x / nqb;
    const int q0 = qb * QBLK;
    const int kbt0 = ks * AITERS;

    {
        const _Float16* Qt = Qp + (size_t)(q0 >> 5) * 16384;
        #pragma unroll
        for (int j = 0; j < 8; ++j)
            gload_lds16(Qt + (size_t)j * 4096 + tid * 8,
                        (char*)Qs + j * 8192 + wave * 1024);
    }
    __syncthreads();

    f32x16 o_acc[2][2];                  // [cht][qt]
    #pragma unroll
    for (int c = 0; c < 2; ++c)
        #pragma unroll
        for (int q = 0; q < 2; ++q)
            #pragma unroll
            for (int r = 0; r < 16; ++r) o_acc[c][q][r] = 0.f;
    float m0 = -INFINITY, m1 = -INFINITY, l0 = 0.f, l1 = 0.f;

    for (int it = 0; it < AITERS; ++it) {
        const _Float16* kp = Kp + ((size_t)(kbt0 + it) * 4 + kt) * 32 * 512;
        half8 ka[32];
        #pragma unroll
        for (int f = 0; f < 32; ++f)
            ka[f] = *(const half8*)(kp + (size_t)f * 512 + lane * 8);

        f32x16 s;
        #pragma unroll
        for (int r = 0; r < 16; ++r) s[r] = 0.f;
        const _Float16* qsb = Qs + qg * 16384;
        __builtin_amdgcn_s_setprio(1);
        #pragma unroll
        for (int f = 0; f < 32; ++f) {
            half8 qb8 = *(const half8*)(qsb + (2 * f + hi32) * 256 + l31 * 8);
            s = __builtin_amdgcn_mfma_f32_32x32x16_f16(ka[f], qb8, s, 0, 0, 0);
        }
        __builtin_amdgcn_s_setprio(0);

        float tmax = s[0];
        #pragma unroll
        for (int r = 1; r < 16; ++r) tmax = fmaxf(tmax, s[r]);
        tmax = fmaxf(tmax, __shfl_xor(tmax, 32));
        if (lane < 32) tm_s[kt][qg * 32 + lane] = tmax;
        __syncthreads();   // BAR1

        float mn0 = fmaxf(fmaxf(fmaxf(tm_s[0][l31], tm_s[1][l31]),
                                fmaxf(tm_s[2][l31], tm_s[3][l31])), m0);
        float mn1 = fmaxf(fmaxf(fmaxf(tm_s[0][32 + l31], tm_s[1][32 + l31]),
                                fmaxf(tm_s[2][32 + l31], tm_s[3][32 + l31])), m1);
        float corr0 = __expf(m0 - mn0);
        float corr1 = __expf(m1 - mn1);
        float mn_own = qg ? mn1 : mn0;

        float p[16];
        float psum = 0.f;
        #pragma unroll
        for (int r = 0; r < 16; ++r) { p[r] = __expf(s[r] - mn_own); psum += p[r]; }
        #pragma unroll
        for (int g = 0; g < 4; ++g) {
            h4 v = {(_Float16)p[4 * g + 0], (_Float16)p[4 * g + 1],
                    (_Float16)p[4 * g + 2], (_Float16)p[4 * g + 3]};
            *(h4*)(Pl + (qg * 8 + kt * 2 + (g >> 1)) * 512 + (g & 1) * 256
                      + l31 * 8 + 4 * hi32) = v;
        }
        psum += __shfl_xor(psum, 32);
        if (lane < 32) ls_s[kt][qg * 32 + lane] = psum;
        __syncthreads();   // BAR2

        l0 = l0 * corr0 + (ls_s[0][l31] + ls_s[1][l31]) + (ls_s[2][l31] + ls_s[3][l31]);
        l1 = l1 * corr1 + (ls_s[0][32 + l31] + ls_s[1][32 + l31])
                        + (ls_s[2][32 + l31] + ls_s[3][32 + l31]);
        m0 = mn0; m1 = mn1;

        half8 va[16];
        #pragma unroll
        for (int cht = 0; cht < 2; ++cht)
            #pragma unroll
            for (int kc = 0; kc < 8; ++kc)
                va[cht * 8 + kc] = *(const half8*)(
                    Vp + (((size_t)(kbt0 + it) * 16 + wave * 2 + cht) * 8 + kc) * 512
                       + lane * 8);

        #pragma unroll
        for (int cht = 0; cht < 2; ++cht)
            #pragma unroll
            for (int r = 0; r < 16; ++r) {
                o_acc[cht][0][r] *= corr0;
                o_acc[cht][1][r] *= corr1;
            }

        __builtin_amdgcn_s_setprio(1);
        #pragma unroll
        for (int qt = 0; qt < 2; ++qt)
            #pragma unroll
            for (int kc = 0; kc < 8; ++kc) {
                half8 pfrag = *(const half8*)(Pl + (qt * 8 + kc) * 512
                                                 + hi32 * 256 + l31 * 8);
                #pragma unroll
                for (int cht = 0; cht < 2; ++cht)
                    o_acc[cht][qt] = __builtin_amdgcn_mfma_f32_32x32x16_f16(
                        va[cht * 8 + kc], pfrag, o_acc[cht][qt], 0, 0, 0);
            }
        __builtin_amdgcn_s_setprio(0);
    }

    float li0 = 1.f / l0, li1 = 1.f / l1;
    #pragma unroll
    for (int cht = 0; cht < 2; ++cht)
        #pragma unroll
        for (int qt = 0; qt < 2; ++qt)
            #pragma unroll
            for (int r = 0; r < 16; ++r) {
                int row = (r & 3) + 8 * (r >> 2) + 4 * hi32;
                int ch = wave * 64 + cht * 32 + row;
                int q = q0 + qt * 32 + l31;
                partH[((size_t)ks * Cd + ch) * Nd + q] =
                    (_Float16)(o_acc[cht][qt][r] * (qt ? li1 : li0));
            }
    if (wave == 0 && lane < 32) {
        marr[(size_t)ks * Nd + q0 + lane] = m0;
        larr[(size_t)ks * Nd + q0 + lane] = l0;
        marr[(size_t)ks * Nd + q0 + 32 + lane] = m1;
        larr[(size_t)ks * Nd + q0 + 32 + lane] = l1;
    }
}

// ---------------- BN stats (per channel, double accumulation) ----------------
__global__ __launch_bounds__(256) void bnstats_k(const float* __restrict__ y,
                                                 const float* __restrict__ gamma,
                                                 const float* __restrict__ beta,
                                                 float* __restrict__ stats) {
    const int c = blockIdx.x;
    const int tid = threadIdx.x;
    double s = 0.0, sq = 0.0;
    for (int b = 0; b < Bd; ++b) {
        const float* p = y + (size_t)(b * Cd + c) * HWd;
        for (int i = tid; i < HWd; i += 256) {
            double v = (double)p[i];
            s += v;
            sq += v * v;
        }
    }
    #pragma unroll
    for (int off = 32; off; off >>= 1) {
        s  += __shfl_xor(s, off, 64);
        sq += __shfl_xor(sq, off, 64);
    }
    __shared__ double ss[4], sqs[4];
    int wid = tid >> 6;
    if ((tid & 63) == 0) { ss[wid] = s; sqs[wid] = sq; }
    __syncthreads();
    if (tid == 0) {
        double S = ss[0] + ss[1] + ss[2] + ss[3];
        double Q = sqs[0] + sqs[1] + sqs[2] + sqs[3];
        double mean = S / (double)Nd;
        double var = Q / (double)Nd - mean * mean;
        float inv = (float)(1.0 / sqrt(var + (double)BN_EPS));
        float sc = gamma[c] * inv;
        stats[c] = sc;
        stats[Cd + c] = beta[c] - (float)mean * sc;
    }
}

__global__ __launch_bounds__(256) void bnapply_k(float* __restrict__ y,
                                                 const float* __restrict__ stats) {
    int idx = blockIdx.x * 256 + threadIdx.x;
    if (idx >= Bd * Cd * HWd) return;
    int c = (idx / HWd) % Cd;
    float v = fmaf(y[idx], stats[c], stats[Cd + c]);
    y[idx] = fmaxf(v, 0.f);
}

extern "C" void kernel_launch(void* const* d_in, const int* in_sizes, int n_in,
                              void* d_out, int out_size, void* d_ws, size_t ws_size,
                              hipStream_t stream) {
    const float* x     = (const float*)d_in[0];
    const float* depth = (const float*)d_in[1];
    const float* w_rgb = (const float*)d_in[2];
    const float* b_rgb = (const float*)d_in[3];
    const float* w_lhs = (const float*)d_in[4];
    const float* b_lhs = (const float*)d_in[5];
    const float* w_rhs = (const float*)d_in[6];
    const float* b_rhs = (const float*)d_in[7];
    const float* w_dec = (const float*)d_in[8];
    const float* b_dec = (const float*)d_in[9];
    const float* gamma = (const float*)d_in[10];
    const float* beta  = (const float*)d_in[11];
    float* out = (float*)d_out;

    char* wsb = (char*)d_ws;
    const size_t NC = (size_t)Nd * Cd;
    _Float16* Qp    = (_Float16*)wsb;
    _Float16* Kp    = (_Float16*)(wsb + NC * 2);
    _Float16* Vp    = (_Float16*)(wsb + NC * 4);
    _Float16* partH = (_Float16*)(wsb + NC * 6);
    float* marr  = (float*)(wsb + NC * 6 + (size_t)NKS * NC * 2);
    float* larr  = marr + (size_t)NKS * Nd;
    float* stats = larr + (size_t)NKS * Nd;
    _Float16* wpLhs = (_Float16*)(stats + 2 * Cd);
    _Float16* wpRhs = wpLhs + (size_t)Cd * Cd;
    _Float16* wpRgb = wpRhs + (size_t)Cd * Cd;
    _Float16* wpDec = wpRgb + (size_t)Cd * Cd;

    wpack_k<<<dim3(128, 4), 256, 0, stream>>>(w_lhs, w_rhs, w_rgb, w_dec,
                                              wpLhs, wpRhs, wpRgb, wpDec);

    dim3 gLin(Nd / 32, 2);
    linproj_k<0, 0><<<gLin, 256, 0, stream>>>(depth, wpLhs, b_lhs, Qp);
    linproj_k<0, 1><<<gLin, 256, 0, stream>>>(depth, wpRhs, b_rhs, Kp);
    linproj_k<0, 2><<<gLin, 256, 0, stream>>>(x, wpRgb, b_rgb, Vp);

    attn_v6_k<<<(Nd / QBLK) * NKS, 512, 0, stream>>>(Qp, Kp, Vp, partH, marr, larr);

    // decoder with fused LSE-merge staging (replaces wprep + merge4 + old decoder)
    lindec_k<<<gLin, 256, 0, stream>>>(partH, marr, larr, wpDec, b_dec, out);

    bnstats_k<<<Cd, 256, 0, stream>>>(out, gamma, beta, stats);
    bnapply_k<<<(Bd * Cd * HWd + 255) / 256, 256, 0, stream>>>(out, stats);
}